// Round 4
// baseline (320.527 us; speedup 1.0000x reference)
//
#include <hip/hip_runtime.h>
#include <hip/hip_bf16.h>
#include <cstdint>

// Problem constants (B=4, S=2048, D2=1024, DV=64, d_k=64)
#define S_LEN 2048
#define D2_   1024
#define DV_   64
#define NB_   4

typedef __bf16 bf16x8 __attribute__((ext_vector_type(8)));
typedef float  f32x16 __attribute__((ext_vector_type(16)));

// fp32 -> bf16 round-to-nearest-even
__device__ __forceinline__ unsigned short f2bf(float f) {
  union { float f; unsigned int u; } v; v.f = f;
  unsigned int r = v.u + 0x7fffu + ((v.u >> 16) & 1u);
  return (unsigned short)(r >> 16);
}

// async global->LDS, 16B per lane (global_load_lds_dwordx4)
__device__ __forceinline__ void async16(const unsigned short* g, unsigned short* l) {
  __builtin_amdgcn_global_load_lds(
      (__attribute__((address_space(1))) void*)g,
      (__attribute__((address_space(3))) void*)l,
      16, 0, 0);
}

// ---------------------------------------------------------------------------
// Kernel 1 (fused prep): per row r:
//   qn[r,:] = bf16( LN(q[r,:]) * 0.125 )      (1/sqrt(64) folded in)
//   kb[r,:] = bf16( k[r,:] )
//   blocks 0..3:  w2[d] = fc_w[d,:] . V       (rank-1 collapse of @fc_w.T)
//   blocks 0..31: zero rowsum[] (d_ws is poisoned 0xAA before every launch)
// ---------------------------------------------------------------------------
__global__ void __launch_bounds__(256) prep_kernel(
    const float* __restrict__ q, const float* __restrict__ k,
    const float* __restrict__ gam, const float* __restrict__ bet,
    const float* __restrict__ V, const float* __restrict__ fw,
    unsigned short* __restrict__ qn, unsigned short* __restrict__ kb,
    float* __restrict__ w2, float* __restrict__ rowsum) {
  const int row = blockIdx.x;
  const int t = threadIdx.x;

  if (row < 32) rowsum[row * 256 + t] = 0.0f;   // 8192 floats total

  // ---- LN(q) ----
  const float4 x = ((const float4*)(q + (size_t)row * D2_))[t];
  float s  = x.x + x.y + x.z + x.w;
  float ss = x.x * x.x + x.y * x.y + x.z * x.z + x.w * x.w;
  #pragma unroll
  for (int o = 32; o > 0; o >>= 1) { s += __shfl_down(s, o); ss += __shfl_down(ss, o); }
  __shared__ float red[8];
  if ((t & 63) == 0) { red[t >> 6] = s; red[(t >> 6) + 4] = ss; }
  __syncthreads();
  const float tot  = red[0] + red[1] + red[2] + red[3];
  const float tots = red[4] + red[5] + red[6] + red[7];
  const float mu  = tot * (1.0f / D2_);
  const float var = tots * (1.0f / D2_) - mu * mu;
  const float rs  = rsqrtf(var + 1e-6f) * 0.125f;
  const float4 gv = ((const float4*)gam)[t];
  const float4 bv = ((const float4*)bet)[t];
  ushort4 o4;
  o4.x = f2bf((x.x - mu) * rs * gv.x + 0.125f * bv.x);
  o4.y = f2bf((x.y - mu) * rs * gv.y + 0.125f * bv.y);
  o4.z = f2bf((x.z - mu) * rs * gv.z + 0.125f * bv.z);
  o4.w = f2bf((x.w - mu) * rs * gv.w + 0.125f * bv.w);
  ((ushort4*)(qn + (size_t)row * D2_))[t] = o4;

  // ---- cast k row ----
  const float4 kx = ((const float4*)(k + (size_t)row * D2_))[t];
  ushort4 k4;
  k4.x = f2bf(kx.x); k4.y = f2bf(kx.y); k4.z = f2bf(kx.z); k4.w = f2bf(kx.w);
  ((ushort4*)(kb + (size_t)row * D2_))[t] = k4;

  // ---- w2 (blocks 0..3) ----
  if (row < 4) {
    const int d = row * 256 + t;
    const float4* r  = (const float4*)(fw + (size_t)d * DV_);
    const float4* vv = (const float4*)V;
    float acc = 0.f;
    #pragma unroll
    for (int j = 0; j < 16; ++j) {
      const float4 a = r[j], b = vv[j];
      acc += a.x * b.x + a.y * b.y + a.z * b.z + a.w * b.w;
    }
    w2[d] = acc;
  }
}

// ---------------------------------------------------------------------------
// Kernel 2: attn = masked( qn @ kb^T );  rowsum += per-row sums (atomics).
// 128x128 tile, BK=32, single LDS buffer (m97 structure — dbuf regressed, R3).
// MFMA 32x32x16, 4 waves x (2x2 frags of 32x32) = 64x64 per wave.
// LDS layout XOR-swizzled in 16B granules: elem offset(row,kg) =
//   row*32 + ((kg ^ (row&3)) * 8),  kg = 16B column-block 0..3.
// -> fragment reads AND the lane-linear DMA writes are bank-conflict-free.
// ---------------------------------------------------------------------------
__global__ void __launch_bounds__(256) attn_gemm_kernel(
    const unsigned short* __restrict__ qn,   // [B*S, D2] bf16
    const unsigned short* __restrict__ kb,   // [B*S, D2] bf16
    const int* __restrict__ mask,            // [B, S, S] int32
    float* __restrict__ attn,                // [B, S, S] f32
    float* __restrict__ rowsum) {            // [B*S] f32 (pre-zeroed)
  __shared__ __align__(16) unsigned short Asm_[128 * 32];   // 8 KiB
  __shared__ __align__(16) unsigned short Bsm_[128 * 32];   // 8 KiB

  const int t  = threadIdx.x;
  const int bn = blockIdx.x * 128;
  const int bm = blockIdx.y * 128;
  const int bt = blockIdx.z;

  // staging: thread t handles rows (t>>2) and (t>>2)+64; its 16B column-block
  // in GLOBAL is kg = (t&3) ^ ((t>>2)&3) so that the forced LDS dest t*16
  // realizes the swizzled layout. Global side stays 64B-segment coalesced.
  const int srow_ = t >> 2;
  const int kg_   = (t & 3) ^ (srow_ & 3);
  const unsigned short* gA = qn + ((size_t)bt * S_LEN + bm + srow_) * D2_ + kg_ * 8;
  const unsigned short* gB = kb + ((size_t)bt * S_LEN + bn + srow_) * D2_ + kg_ * 8;
  unsigned short* lA = Asm_ + t * 8;
  unsigned short* lB = Bsm_ + t * 8;

  const int lane = t & 63;
  const int w    = t >> 6;
  const int wm   = (w >> 1) * 64;   // wave row offset in tile
  const int wn   = (w & 1) * 64;    // wave col offset in tile
  const int col  = lane & 31;       // n (and m) index within a 32x32 frag
  const int half = lane >> 5;       // k-half selector for A/B frags

  // A/B frag LDS element offsets: row*32 + ((kg ^ (row&3))*8); row&3 == lane&3
  const int x0 = (half ^ (lane & 3)) * 8;        // s=0: kg = half
  const int x1 = ((2 + half) ^ (lane & 3)) * 8;  // s=1: kg = 2+half

  f32x16 acc[2][2] = {};

  for (int k0 = 0; k0 < D2_; k0 += 32) {
    async16(gA, lA);
    async16(gA + 64 * D2_, lA + 2048);
    async16(gB, lB);
    async16(gB + 64 * D2_, lB + 2048);
    gA += 32; gB += 32;
    __syncthreads();   // drains vmcnt(0): staged tile visible

    bf16x8 af[2][2], bfv[2][2];   // [fm|fn][s]
    #pragma unroll
    for (int f = 0; f < 2; ++f) {
      const int ra = (wm + f * 32 + col) * 32;
      const int rb = (wn + f * 32 + col) * 32;
      af[f][0]  = *(const bf16x8*)(Asm_ + ra + x0);
      af[f][1]  = *(const bf16x8*)(Asm_ + ra + x1);
      bfv[f][0] = *(const bf16x8*)(Bsm_ + rb + x0);
      bfv[f][1] = *(const bf16x8*)(Bsm_ + rb + x1);
    }
    #pragma unroll
    for (int s = 0; s < 2; ++s)
      #pragma unroll
      for (int fm = 0; fm < 2; ++fm)
        #pragma unroll
        for (int fn = 0; fn < 2; ++fn)
          acc[fm][fn] = __builtin_amdgcn_mfma_f32_32x32x16_bf16(
              af[fm][s], bfv[fn][s], acc[fm][fn], 0, 0, 0);
    __syncthreads();
  }

  // epilogue. C/D layout (m74/m101): col = lane&31,
  // row = (reg&3) + 8*(reg>>2) + 4*(lane>>5).
  // Apply mask, store attn, and shuffle-reduce each row's 64-col slice
  // (width 32: the two k-halves own different rows) -> one atomicAdd/row.
  #pragma unroll
  for (int fm = 0; fm < 2; ++fm) {
    #pragma unroll
    for (int r = 0; r < 16; ++r) {
      const int srow = bm + wm + fm * 32 + (r & 3) + 8 * (r >> 2) + 4 * half;
      const size_t base = ((size_t)bt * S_LEN + srow) * S_LEN + bn + wn;
      float v0 = acc[fm][0][r];
      float v1 = acc[fm][1][r];
      v0 = mask[base + col] ? 0.0f : v0;
      v1 = mask[base + 32 + col] ? 0.0f : v1;
      attn[base + col]      = v0;
      attn[base + 32 + col] = v1;
      float s = v0 + v1;
      #pragma unroll
      for (int o = 16; o > 0; o >>= 1) s += __shfl_down(s, o, 32);
      if (col == 0) atomicAdd(rowsum + (size_t)bt * S_LEN + srow, s);
    }
  }
}

// ---------------------------------------------------------------------------
// Kernel 3: out[row,:] = rowsum[row] * w2[:] + fc_b[:] + q[row,:]
// (never touches attn — rowsum was accumulated in the GEMM epilogue).
// Overwrites the out-region that temporarily held qn/kb; reads nothing
// from it, safe under stream ordering.
// ---------------------------------------------------------------------------
__global__ void __launch_bounds__(256) out_kernel(
    const float* __restrict__ rowsum, const float* __restrict__ q,
    const float* __restrict__ w2, const float* __restrict__ fcb,
    float* __restrict__ out) {
  const int row = blockIdx.x;
  const int t = threadIdx.x;
  const float rs = rowsum[row];
  const float4 wv = ((const float4*)w2)[t];
  const float4 bv = ((const float4*)fcb)[t];
  const float4 qv = ((const float4*)(q + (size_t)row * D2_))[t];
  float4 o4;
  o4.x = rs * wv.x + bv.x + qv.x;
  o4.y = rs * wv.y + bv.y + qv.y;
  o4.z = rs * wv.z + bv.z + qv.z;
  o4.w = rs * wv.w + bv.w + qv.w;
  ((float4*)(out + (size_t)row * D2_))[t] = o4;
}

// ---------------------------------------------------------------------------
extern "C" void kernel_launch(void* const* d_in, const int* in_sizes, int n_in,
                              void* d_out, int out_size, void* d_ws, size_t ws_size,
                              hipStream_t stream) {
  (void)in_sizes; (void)n_in; (void)out_size; (void)ws_size;
  const float* q    = (const float*)d_in[0];
  const float* k    = (const float*)d_in[1];
  /* d_in[2] == v: provably unused by the reference computation */
  const int*   mask = (const int*)d_in[3];
  const float* V    = (const float*)d_in[4];
  const float* fw   = (const float*)d_in[5];
  const float* fcb  = (const float*)d_in[6];
  const float* lg   = (const float*)d_in[7];
  const float* lb   = (const float*)d_in[8];

  float* out  = (float*)d_out;                          // [B,S,D2]  32 MiB
  float* attn = out + (size_t)NB_ * S_LEN * D2_;        // [B,S,S]   64 MiB

  // qn/kb live INSIDE the out-region (exactly 32 MiB), dead until out_kernel
  // overwrites it last.  d_ws: w2 (4 KiB) + rowsum (32 KiB).
  unsigned short* qn = (unsigned short*)out;                     // 16 MiB
  unsigned short* kb = qn + (size_t)NB_ * S_LEN * D2_;           // 16 MiB
  float* w2     = (float*)d_ws;                                  // 1024 f
  float* rowsum = w2 + D2_;                                      // 8192 f

  prep_kernel<<<NB_ * S_LEN, 256, 0, stream>>>(q, k, lg, lb, V, fw, qn, kb, w2, rowsum);
  attn_gemm_kernel<<<dim3(S_LEN / 128, S_LEN / 128, NB_), 256, 0, stream>>>(qn, kb, mask, attn, rowsum);
  out_kernel<<<NB_ * S_LEN, 256, 0, stream>>>(rowsum, q, w2, fcb, out);
}

// Round 5
// 275.347 us; speedup vs baseline: 1.1641x; 1.1641x over previous
//
#include <hip/hip_runtime.h>
#include <hip/hip_bf16.h>
#include <cstdint>

// Problem constants (B=4, S=2048, D2=1024, DV=64, d_k=64)
#define S_LEN 2048
#define D2_   1024
#define DV_   64
#define NB_   4

typedef __bf16 bf16x8 __attribute__((ext_vector_type(8)));
typedef float  f32x4  __attribute__((ext_vector_type(4)));

// fp32 -> bf16 round-to-nearest-even
__device__ __forceinline__ unsigned short f2bf(float f) {
  union { float f; unsigned int u; } v; v.f = f;
  unsigned int r = v.u + 0x7fffu + ((v.u >> 16) & 1u);
  return (unsigned short)(r >> 16);
}

// async global->LDS, 16B per lane (global_load_lds_dwordx4)
__device__ __forceinline__ void async16(const unsigned short* g, unsigned short* l) {
  __builtin_amdgcn_global_load_lds(
      (__attribute__((address_space(1))) void*)g,
      (__attribute__((address_space(3))) void*)l,
      16, 0, 0);
}

// ---------------------------------------------------------------------------
// Kernel 1 (fused prep): per row r:
//   qn[r,:] = bf16( LN(q[r,:]) * 0.125 )      (1/sqrt(64) folded in)
//   kb[r,:] = bf16( k[r,:] )
//   blocks 0..3:  w2[d] = fc_w[d,:] . V       (rank-1 collapse of @fc_w.T)
//   blocks 0..31: zero rowsum[] (d_ws is poisoned 0xAA before every launch)
// ---------------------------------------------------------------------------
__global__ void __launch_bounds__(256) prep_kernel(
    const float* __restrict__ q, const float* __restrict__ k,
    const float* __restrict__ gam, const float* __restrict__ bet,
    const float* __restrict__ V, const float* __restrict__ fw,
    unsigned short* __restrict__ qn, unsigned short* __restrict__ kb,
    float* __restrict__ w2, float* __restrict__ rowsum) {
  const int row = blockIdx.x;
  const int t = threadIdx.x;

  if (row < 32) rowsum[row * 256 + t] = 0.0f;   // 8192 floats total

  // ---- LN(q) ----
  const float4 x = ((const float4*)(q + (size_t)row * D2_))[t];
  float s  = x.x + x.y + x.z + x.w;
  float ss = x.x * x.x + x.y * x.y + x.z * x.z + x.w * x.w;
  #pragma unroll
  for (int o = 32; o > 0; o >>= 1) { s += __shfl_down(s, o); ss += __shfl_down(ss, o); }
  __shared__ float red[8];
  if ((t & 63) == 0) { red[t >> 6] = s; red[(t >> 6) + 4] = ss; }
  __syncthreads();
  const float tot  = red[0] + red[1] + red[2] + red[3];
  const float tots = red[4] + red[5] + red[6] + red[7];
  const float mu  = tot * (1.0f / D2_);
  const float var = tots * (1.0f / D2_) - mu * mu;
  const float rs  = rsqrtf(var + 1e-6f) * 0.125f;
  const float4 gv = ((const float4*)gam)[t];
  const float4 bv = ((const float4*)bet)[t];
  ushort4 o4;
  o4.x = f2bf((x.x - mu) * rs * gv.x + 0.125f * bv.x);
  o4.y = f2bf((x.y - mu) * rs * gv.y + 0.125f * bv.y);
  o4.z = f2bf((x.z - mu) * rs * gv.z + 0.125f * bv.z);
  o4.w = f2bf((x.w - mu) * rs * gv.w + 0.125f * bv.w);
  ((ushort4*)(qn + (size_t)row * D2_))[t] = o4;

  // ---- cast k row ----
  const float4 kx = ((const float4*)(k + (size_t)row * D2_))[t];
  ushort4 k4;
  k4.x = f2bf(kx.x); k4.y = f2bf(kx.y); k4.z = f2bf(kx.z); k4.w = f2bf(kx.w);
  ((ushort4*)(kb + (size_t)row * D2_))[t] = k4;

  // ---- w2 (blocks 0..3) ----
  if (row < 4) {
    const int d = row * 256 + t;
    const float4* r  = (const float4*)(fw + (size_t)d * DV_);
    const float4* vv = (const float4*)V;
    float acc = 0.f;
    #pragma unroll
    for (int j = 0; j < 16; ++j) {
      const float4 a = r[j], b = vv[j];
      acc += a.x * b.x + a.y * b.y + a.z * b.z + a.w * b.w;
    }
    w2[d] = acc;
  }
}

// ---------------------------------------------------------------------------
// Kernel 2: attn = masked( qn @ kb^T );  rowsum += per-row sums.
// R2 structure (measured best): single LDS buffer, 2 barriers/iter,
// 16x16x32 MFMA, 4 waves x 4x4 frags = 64x64/wave.  Changes vs R2:
//  * BK=64: 16 iters, 8 DMA loads in flight per barrier (halves drains).
//  * 16B-granule slot swizzle: granule (row, kg) stored at slot kg^(row&7)
//    -> fragment reads walk quads 0..7 across lanes 0..7 (lane-linear-like,
//    the m134-good pattern); DMA dest stays lane-linear (contract).
//  * MFMA operand order SWAPPED: mfma(kb_frag, qn_frag, acc) so
//    reg quad = 4 consecutive attn COLUMNS -> float4/int4 epilogue.
// ---------------------------------------------------------------------------
__global__ void __launch_bounds__(256, 4) attn_gemm_kernel(
    const unsigned short* __restrict__ qn,   // [B*S, D2] bf16
    const unsigned short* __restrict__ kb,   // [B*S, D2] bf16
    const int* __restrict__ mask,            // [B, S, S] int32
    float* __restrict__ attn,                // [B, S, S] f32
    float* __restrict__ rowsum) {            // [B*S] f32 (pre-zeroed)
  __shared__ __align__(16) unsigned short Asm_[128 * 64];   // 16 KiB
  __shared__ __align__(16) unsigned short Bsm_[128 * 64];   // 16 KiB

  const int t  = threadIdx.x;
  const int bn = blockIdx.x * 128;
  const int bm = blockIdx.y * 128;
  const int bt = blockIdx.z;

  // staging: thread t covers rows (t>>3)+32j, j=0..3. Forced LDS dest t*16B
  // = (row&31 part, slot t&7); realize slot = kg ^ (row&7) by permuting the
  // GLOBAL granule: kg = (t&7) ^ ((t>>3)&7). 8 consecutive threads still
  // cover one full 128B row segment (permuted within) -> coalesced.
  const int srow_ = t >> 3;
  const int kg_   = (t & 7) ^ (srow_ & 7);
  const unsigned short* gA = qn + ((size_t)bt * S_LEN + bm + srow_) * D2_ + kg_ * 8;
  const unsigned short* gB = kb + ((size_t)bt * S_LEN + bn + srow_) * D2_ + kg_ * 8;
  unsigned short* lA = Asm_ + t * 8;
  unsigned short* lB = Bsm_ + t * 8;

  const int lane = t & 63;
  const int w  = t >> 6;
  const int wm = (w >> 1) * 64;   // wave row (m) offset in tile
  const int wn = (w & 1) * 64;    // wave col (n) offset in tile
  const int lr = lane & 15;
  const int lg = lane >> 4;

  f32x4 acc[4][4] = {};           // [fm][fn]

  for (int k0 = 0; k0 < D2_; k0 += 64) {
    #pragma unroll
    for (int j = 0; j < 4; ++j) {
      async16(gA + j * 32 * D2_, lA + j * 2048);
      async16(gB + j * 32 * D2_, lB + j * 2048);
    }
    gA += 64; gB += 64;
    __syncthreads();   // drains vmcnt(0): staged tile visible

    #pragma unroll
    for (int ks = 0; ks < 2; ++ks) {
      bf16x8 af[4], bfv[4];
      #pragma unroll
      for (int f = 0; f < 4; ++f) {
        // frag element (row, k-granule ks*4+lg) -> slot (ks*4+lg)^(row&7);
        // row&7 == lr&7 (wm, f*16 are multiples of 16... wm mult of 64, f*16 mult of 16, both &7==0... f*16&7==0 yes)
        const int sl = ((ks << 2) + lg) ^ (lr & 7);
        af[f]  = *(const bf16x8*)(Asm_ + (wm + f * 16 + lr) * 64 + sl * 8);
        bfv[f] = *(const bf16x8*)(Bsm_ + (wn + f * 16 + lr) * 64 + sl * 8);
      }
      #pragma unroll
      for (int fm = 0; fm < 4; ++fm)
        #pragma unroll
        for (int fn = 0; fn < 4; ++fn)
          acc[fm][fn] = __builtin_amdgcn_mfma_f32_16x16x32_bf16(
              bfv[fn], af[fm], acc[fm][fn], 0, 0, 0);   // NOTE swapped order
    }
    __syncthreads();   // all reads done before next iter's DMA overwrites
  }

  // epilogue. With swapped operands: first op (kb) -> "row"=(lane>>4)*4+reg
  // = attn COLUMN n; second op (qn) -> "col"=lane&15 = attn ROW m.
  // Lane (lr,lg), frag (fm,fn): m = bm+wm+fm*16+lr (same for all 16 vals),
  // n = bn+wn+fn*16+lg*4+r  -> 4 consecutive n per reg quad.
  #pragma unroll
  for (int fm = 0; fm < 4; ++fm) {
    const int m = bm + wm + fm * 16 + lr;
    const size_t rowbase = ((size_t)bt * S_LEN + m) * S_LEN;
    float s = 0.f;
    #pragma unroll
    for (int fn = 0; fn < 4; ++fn) {
      const int n0 = bn + wn + fn * 16 + lg * 4;
      const int4 mk = *(const int4*)(mask + rowbase + n0);
      float4 v;
      v.x = mk.x ? 0.0f : acc[fm][fn][0];
      v.y = mk.y ? 0.0f : acc[fm][fn][1];
      v.z = mk.z ? 0.0f : acc[fm][fn][2];
      v.w = mk.w ? 0.0f : acc[fm][fn][3];
      *(float4*)(attn + rowbase + n0) = v;
      s += v.x + v.y + v.z + v.w;
    }
    // reduce across lg groups (lanes sharing lr): xor 16, 32
    s += __shfl_xor(s, 16);
    s += __shfl_xor(s, 32);
    if (lane < 16) atomicAdd(rowsum + (size_t)bt * S_LEN + m, s);
  }
}

// ---------------------------------------------------------------------------
// Kernel 3: out[row,:] = rowsum[row] * w2[:] + fc_b[:] + q[row,:]
// (never touches attn).  Overwrites the out-region that held qn/kb; reads
// nothing from it — safe under stream ordering.
// ---------------------------------------------------------------------------
__global__ void __launch_bounds__(256) out_kernel(
    const float* __restrict__ rowsum, const float* __restrict__ q,
    const float* __restrict__ w2, const float* __restrict__ fcb,
    float* __restrict__ out) {
  const int row = blockIdx.x;
  const int t = threadIdx.x;
  const float rs = rowsum[row];
  const float4 wv = ((const float4*)w2)[t];
  const float4 bv = ((const float4*)fcb)[t];
  const float4 qv = ((const float4*)(q + (size_t)row * D2_))[t];
  float4 o4;
  o4.x = rs * wv.x + bv.x + qv.x;
  o4.y = rs * wv.y + bv.y + qv.y;
  o4.z = rs * wv.z + bv.z + qv.z;
  o4.w = rs * wv.w + bv.w + qv.w;
  ((float4*)(out + (size_t)row * D2_))[t] = o4;
}

// ---------------------------------------------------------------------------
extern "C" void kernel_launch(void* const* d_in, const int* in_sizes, int n_in,
                              void* d_out, int out_size, void* d_ws, size_t ws_size,
                              hipStream_t stream) {
  (void)in_sizes; (void)n_in; (void)out_size; (void)ws_size;
  const float* q    = (const float*)d_in[0];
  const float* k    = (const float*)d_in[1];
  /* d_in[2] == v: provably unused by the reference computation */
  const int*   mask = (const int*)d_in[3];
  const float* V    = (const float*)d_in[4];
  const float* fw   = (const float*)d_in[5];
  const float* fcb  = (const float*)d_in[6];
  const float* lg   = (const float*)d_in[7];
  const float* lb   = (const float*)d_in[8];

  float* out  = (float*)d_out;                          // [B,S,D2]  32 MiB
  float* attn = out + (size_t)NB_ * S_LEN * D2_;        // [B,S,S]   64 MiB

  // qn/kb live INSIDE the out-region (exactly 32 MiB), dead until out_kernel
  // overwrites it last.  d_ws: w2 (4 KiB) + rowsum (32 KiB).
  unsigned short* qn = (unsigned short*)out;                     // 16 MiB
  unsigned short* kb = qn + (size_t)NB_ * S_LEN * D2_;           // 16 MiB
  float* w2     = (float*)d_ws;                                  // 1024 f
  float* rowsum = w2 + D2_;                                      // 8192 f

  prep_kernel<<<NB_ * S_LEN, 256, 0, stream>>>(q, k, lg, lb, V, fw, qn, kb, w2, rowsum);
  attn_gemm_kernel<<<dim3(S_LEN / 128, S_LEN / 128, NB_), 256, 0, stream>>>(qn, kb, mask, attn, rowsum);
  out_kernel<<<NB_ * S_LEN, 256, 0, stream>>>(rowsum, q, w2, fcb, out);
}

// Round 6
// 271.642 us; speedup vs baseline: 1.1800x; 1.0136x over previous
//
#include <hip/hip_runtime.h>
#include <hip/hip_bf16.h>
#include <cstdint>

// Problem constants (B=4, S=2048, D2=1024, DV=64, d_k=64)
#define S_LEN 2048
#define D2_   1024
#define DV_   64
#define NB_   4

typedef __bf16 bf16x8 __attribute__((ext_vector_type(8)));
typedef float  f32x4  __attribute__((ext_vector_type(4)));

// fp32 -> bf16 round-to-nearest-even
__device__ __forceinline__ unsigned short f2bf(float f) {
  union { float f; unsigned int u; } v; v.f = f;
  unsigned int r = v.u + 0x7fffu + ((v.u >> 16) & 1u);
  return (unsigned short)(r >> 16);
}

// async global->LDS, 16B per lane (global_load_lds_dwordx4)
__device__ __forceinline__ void async16(const unsigned short* g, unsigned short* l) {
  __builtin_amdgcn_global_load_lds(
      (__attribute__((address_space(1))) void*)g,
      (__attribute__((address_space(3))) void*)l,
      16, 0, 0);
}

// ---------------------------------------------------------------------------
// Kernel 1 (fused prep): per row r:
//   qn[r,:] = bf16( LN(q[r,:]) * 0.125 )      (1/sqrt(64) folded in)
//   kb[r,:] = bf16( k[r,:] )
//   blocks 0..3:  w2[d] = fc_w[d,:] . V       (rank-1 collapse of @fc_w.T)
//   blocks 0..31: zero rowsum[] (d_ws is poisoned 0xAA before every launch)
// ---------------------------------------------------------------------------
__global__ void __launch_bounds__(256) prep_kernel(
    const float* __restrict__ q, const float* __restrict__ k,
    const float* __restrict__ gam, const float* __restrict__ bet,
    const float* __restrict__ V, const float* __restrict__ fw,
    unsigned short* __restrict__ qn, unsigned short* __restrict__ kb,
    float* __restrict__ w2, float* __restrict__ rowsum) {
  const int row = blockIdx.x;
  const int t = threadIdx.x;

  if (row < 32) rowsum[row * 256 + t] = 0.0f;   // 8192 floats total

  // ---- LN(q) ----
  const float4 x = ((const float4*)(q + (size_t)row * D2_))[t];
  float s  = x.x + x.y + x.z + x.w;
  float ss = x.x * x.x + x.y * x.y + x.z * x.z + x.w * x.w;
  #pragma unroll
  for (int o = 32; o > 0; o >>= 1) { s += __shfl_down(s, o); ss += __shfl_down(ss, o); }
  __shared__ float red[8];
  if ((t & 63) == 0) { red[t >> 6] = s; red[(t >> 6) + 4] = ss; }
  __syncthreads();
  const float tot  = red[0] + red[1] + red[2] + red[3];
  const float tots = red[4] + red[5] + red[6] + red[7];
  const float mu  = tot * (1.0f / D2_);
  const float var = tots * (1.0f / D2_) - mu * mu;
  const float rs  = rsqrtf(var + 1e-6f) * 0.125f;
  const float4 gv = ((const float4*)gam)[t];
  const float4 bv = ((const float4*)bet)[t];
  ushort4 o4;
  o4.x = f2bf((x.x - mu) * rs * gv.x + 0.125f * bv.x);
  o4.y = f2bf((x.y - mu) * rs * gv.y + 0.125f * bv.y);
  o4.z = f2bf((x.z - mu) * rs * gv.z + 0.125f * bv.z);
  o4.w = f2bf((x.w - mu) * rs * gv.w + 0.125f * bv.w);
  ((ushort4*)(qn + (size_t)row * D2_))[t] = o4;

  // ---- cast k row ----
  const float4 kx = ((const float4*)(k + (size_t)row * D2_))[t];
  ushort4 k4;
  k4.x = f2bf(kx.x); k4.y = f2bf(kx.y); k4.z = f2bf(kx.z); k4.w = f2bf(kx.w);
  ((ushort4*)(kb + (size_t)row * D2_))[t] = k4;

  // ---- w2 (blocks 0..3) ----
  if (row < 4) {
    const int d = row * 256 + t;
    const float4* r  = (const float4*)(fw + (size_t)d * DV_);
    const float4* vv = (const float4*)V;
    float acc = 0.f;
    #pragma unroll
    for (int j = 0; j < 16; ++j) {
      const float4 a = r[j], b = vv[j];
      acc += a.x * b.x + a.y * b.y + a.z * b.z + a.w * b.w;
    }
    w2[d] = acc;
  }
}

// ---------------------------------------------------------------------------
// Kernel 2: attn = masked( qn @ kb^T );  rowsum += per-row sums.
// Tile 128(m) x 64(n), BK=64 -> grid 32x16x4 = 2048 blocks (8/CU) for
// occupancy (R5's 1024-block grid capped residency at ~2.5 blocks/CU).
// Single LDS buffer, 2 barriers/iter (dbuf regressed in R3), row&7 16B-slot
// swizzle (0 bank conflicts, measured R5), swapped-operand MFMA so reg quad
// = 4 consecutive attn cols. Mask slice prefetched to registers BEFORE the
// K-loop: its latency is absorbed by iter 0 instead of the epilogue.
// 4 waves: wave (w>>1) -> m half (64), (w&1) -> n half (32);
// frags: fm 0..3 (m), fn 0..1 (n), 16x16x32 MFMA.
// ---------------------------------------------------------------------------
__global__ void __launch_bounds__(256, 4) attn_gemm_kernel(
    const unsigned short* __restrict__ qn,   // [B*S, D2] bf16
    const unsigned short* __restrict__ kb,   // [B*S, D2] bf16
    const int* __restrict__ mask,            // [B, S, S] int32
    float* __restrict__ attn,                // [B, S, S] f32
    float* __restrict__ rowsum) {            // [B*S] f32 (pre-zeroed)
  __shared__ __align__(16) unsigned short Asm_[128 * 64];   // 16 KiB
  __shared__ __align__(16) unsigned short Bsm_[64 * 64];    //  8 KiB

  const int t  = threadIdx.x;
  const int bn = blockIdx.x * 64;
  const int bm = blockIdx.y * 128;
  const int bt = blockIdx.z;

  // staging: thread t covers row (t>>3)+32j, 16B-granule slot t&7; realize
  // LDS slot = kg ^ (row&7) by permuting the GLOBAL granule (R5 pattern,
  // measured 0 conflicts). 8 consecutive threads cover one 128B row segment.
  const int srow_ = t >> 3;
  const int kg_   = (t & 7) ^ (srow_ & 7);
  const unsigned short* gA = qn + ((size_t)bt * S_LEN + bm + srow_) * D2_ + kg_ * 8;
  const unsigned short* gB = kb + ((size_t)bt * S_LEN + bn + srow_) * D2_ + kg_ * 8;
  unsigned short* lA = Asm_ + t * 8;
  unsigned short* lB = Bsm_ + t * 8;

  const int lane = t & 63;
  const int w  = t >> 6;
  const int wm = (w >> 1) * 64;   // wave m offset in tile (0/64)
  const int wn = (w & 1) * 32;    // wave n offset in tile (0/32)
  const int lr = lane & 15;
  const int lg = lane >> 4;

  // mask prefetch: lane's attn coords: m = bm+wm+fm*16+lr (per fm),
  // n0 = bn+wn+fn*16+lg*4 (per fn). 8 int4 loads, in flight across K-loop.
  const int m_base = bm + wm + lr;
  const size_t rb0 = ((size_t)bt * S_LEN) * S_LEN;
  int4 mk[4][2];
  #pragma unroll
  for (int fm = 0; fm < 4; ++fm)
    #pragma unroll
    for (int fn = 0; fn < 2; ++fn)
      mk[fm][fn] = *(const int4*)(mask + rb0 + (size_t)(m_base + fm * 16) * S_LEN
                                  + bn + wn + fn * 16 + lg * 4);

  f32x4 acc[4][2] = {};           // [fm][fn]

  for (int k0 = 0; k0 < D2_; k0 += 64) {
    #pragma unroll
    for (int j = 0; j < 4; ++j)
      async16(gA + j * 32 * D2_, lA + j * 2048);
    #pragma unroll
    for (int j = 0; j < 2; ++j)
      async16(gB + j * 32 * D2_, lB + j * 2048);
    gA += 64; gB += 64;
    __syncthreads();   // drains vmcnt(0): staged tile (and mask, once) landed

    #pragma unroll
    for (int ks = 0; ks < 2; ++ks) {
      const int sl = ((ks << 2) + lg) ^ (lr & 7);   // swizzled 16B slot
      bf16x8 af[4], bfv[2];
      #pragma unroll
      for (int f = 0; f < 4; ++f)
        af[f]  = *(const bf16x8*)(Asm_ + (wm + f * 16 + lr) * 64 + sl * 8);
      #pragma unroll
      for (int f = 0; f < 2; ++f)
        bfv[f] = *(const bf16x8*)(Bsm_ + (wn + f * 16 + lr) * 64 + sl * 8);
      #pragma unroll
      for (int fm = 0; fm < 4; ++fm)
        #pragma unroll
        for (int fn = 0; fn < 2; ++fn)
          acc[fm][fn] = __builtin_amdgcn_mfma_f32_16x16x32_bf16(
              bfv[fn], af[fm], acc[fm][fn], 0, 0, 0);   // swapped order
    }
    __syncthreads();   // all reads done before next iter's DMA overwrites
  }

  // epilogue: pure stores (mask already in registers) + rowsum reduce.
  #pragma unroll
  for (int fm = 0; fm < 4; ++fm) {
    const int m = m_base + fm * 16;
    const size_t rowbase = rb0 + (size_t)m * S_LEN;
    float s = 0.f;
    #pragma unroll
    for (int fn = 0; fn < 2; ++fn) {
      const int n0 = bn + wn + fn * 16 + lg * 4;
      float4 v;
      v.x = mk[fm][fn].x ? 0.0f : acc[fm][fn][0];
      v.y = mk[fm][fn].y ? 0.0f : acc[fm][fn][1];
      v.z = mk[fm][fn].z ? 0.0f : acc[fm][fn][2];
      v.w = mk[fm][fn].w ? 0.0f : acc[fm][fn][3];
      *(float4*)(attn + rowbase + n0) = v;
      s += v.x + v.y + v.z + v.w;
    }
    // reduce across the 4 lg groups sharing this row
    s += __shfl_xor(s, 16);
    s += __shfl_xor(s, 32);
    if (lane < 16) atomicAdd(rowsum + (size_t)bt * S_LEN + m, s);
  }
}

// ---------------------------------------------------------------------------
// Kernel 3: out[row,:] = rowsum[row] * w2[:] + fc_b[:] + q[row,:]
// (never touches attn).  Overwrites the out-region that held qn/kb; reads
// nothing from it — safe under stream ordering.
// ---------------------------------------------------------------------------
__global__ void __launch_bounds__(256) out_kernel(
    const float* __restrict__ rowsum, const float* __restrict__ q,
    const float* __restrict__ w2, const float* __restrict__ fcb,
    float* __restrict__ out) {
  const int row = blockIdx.x;
  const int t = threadIdx.x;
  const float rs = rowsum[row];
  const float4 wv = ((const float4*)w2)[t];
  const float4 bv = ((const float4*)fcb)[t];
  const float4 qv = ((const float4*)(q + (size_t)row * D2_))[t];
  float4 o4;
  o4.x = rs * wv.x + bv.x + qv.x;
  o4.y = rs * wv.y + bv.y + qv.y;
  o4.z = rs * wv.z + bv.z + qv.z;
  o4.w = rs * wv.w + bv.w + qv.w;
  ((float4*)(out + (size_t)row * D2_))[t] = o4;
}

// ---------------------------------------------------------------------------
extern "C" void kernel_launch(void* const* d_in, const int* in_sizes, int n_in,
                              void* d_out, int out_size, void* d_ws, size_t ws_size,
                              hipStream_t stream) {
  (void)in_sizes; (void)n_in; (void)out_size; (void)ws_size;
  const float* q    = (const float*)d_in[0];
  const float* k    = (const float*)d_in[1];
  /* d_in[2] == v: provably unused by the reference computation */
  const int*   mask = (const int*)d_in[3];
  const float* V    = (const float*)d_in[4];
  const float* fw   = (const float*)d_in[5];
  const float* fcb  = (const float*)d_in[6];
  const float* lg   = (const float*)d_in[7];
  const float* lb   = (const float*)d_in[8];

  float* out  = (float*)d_out;                          // [B,S,D2]  32 MiB
  float* attn = out + (size_t)NB_ * S_LEN * D2_;        // [B,S,S]   64 MiB

  // qn/kb live INSIDE the out-region (exactly 32 MiB), dead until out_kernel
  // overwrites it last.  d_ws: w2 (4 KiB) + rowsum (32 KiB).
  unsigned short* qn = (unsigned short*)out;                     // 16 MiB
  unsigned short* kb = qn + (size_t)NB_ * S_LEN * D2_;           // 16 MiB
  float* w2     = (float*)d_ws;                                  // 1024 f
  float* rowsum = w2 + D2_;                                      // 8192 f

  prep_kernel<<<NB_ * S_LEN, 256, 0, stream>>>(q, k, lg, lb, V, fw, qn, kb, w2, rowsum);
  attn_gemm_kernel<<<dim3(S_LEN / 64, S_LEN / 128, NB_), 256, 0, stream>>>(qn, kb, mask, attn, rowsum);
  out_kernel<<<NB_ * S_LEN, 256, 0, stream>>>(rowsum, q, w2, fcb, out);
}

// Round 7
// 271.414 us; speedup vs baseline: 1.1810x; 1.0008x over previous
//
#include <hip/hip_runtime.h>
#include <hip/hip_bf16.h>
#include <cstdint>

// Problem constants (B=4, S=2048, D2=1024, DV=64, d_k=64)
#define S_LEN 2048
#define D2_   1024
#define DV_   64
#define NB_   4

typedef __bf16 bf16x8 __attribute__((ext_vector_type(8)));
typedef float  f32x4  __attribute__((ext_vector_type(4)));

// fp32 -> bf16 round-to-nearest-even
__device__ __forceinline__ unsigned short f2bf(float f) {
  union { float f; unsigned int u; } v; v.f = f;
  unsigned int r = v.u + 0x7fffu + ((v.u >> 16) & 1u);
  return (unsigned short)(r >> 16);
}

// async global->LDS, 16B per lane (global_load_lds_dwordx4)
__device__ __forceinline__ void async16(const unsigned short* g, unsigned short* l) {
  __builtin_amdgcn_global_load_lds(
      (__attribute__((address_space(1))) void*)g,
      (__attribute__((address_space(3))) void*)l,
      16, 0, 0);
}

// ---------------------------------------------------------------------------
// Kernel 1 (fused prep): per row r:
//   qn[r,:] = bf16( LN(q[r,:]) * 0.125 )      (1/sqrt(64) folded in)
//   kb[r,:] = bf16( k[r,:] )
//   blocks 0..3:  w2[d] = fc_w[d,:] . V       (rank-1 collapse of @fc_w.T)
//   blocks 0..31: zero rowsum[] (d_ws is poisoned 0xAA before every launch)
// ---------------------------------------------------------------------------
__global__ void __launch_bounds__(256) prep_kernel(
    const float* __restrict__ q, const float* __restrict__ k,
    const float* __restrict__ gam, const float* __restrict__ bet,
    const float* __restrict__ V, const float* __restrict__ fw,
    unsigned short* __restrict__ qn, unsigned short* __restrict__ kb,
    float* __restrict__ w2, float* __restrict__ rowsum) {
  const int row = blockIdx.x;
  const int t = threadIdx.x;

  if (row < 32) rowsum[row * 256 + t] = 0.0f;   // 8192 floats total

  // ---- LN(q) ----
  const float4 x = ((const float4*)(q + (size_t)row * D2_))[t];
  float s  = x.x + x.y + x.z + x.w;
  float ss = x.x * x.x + x.y * x.y + x.z * x.z + x.w * x.w;
  #pragma unroll
  for (int o = 32; o > 0; o >>= 1) { s += __shfl_down(s, o); ss += __shfl_down(ss, o); }
  __shared__ float red[8];
  if ((t & 63) == 0) { red[t >> 6] = s; red[(t >> 6) + 4] = ss; }
  __syncthreads();
  const float tot  = red[0] + red[1] + red[2] + red[3];
  const float tots = red[4] + red[5] + red[6] + red[7];
  const float mu  = tot * (1.0f / D2_);
  const float var = tots * (1.0f / D2_) - mu * mu;
  const float rs  = rsqrtf(var + 1e-6f) * 0.125f;
  const float4 gv = ((const float4*)gam)[t];
  const float4 bv = ((const float4*)bet)[t];
  ushort4 o4;
  o4.x = f2bf((x.x - mu) * rs * gv.x + 0.125f * bv.x);
  o4.y = f2bf((x.y - mu) * rs * gv.y + 0.125f * bv.y);
  o4.z = f2bf((x.z - mu) * rs * gv.z + 0.125f * bv.z);
  o4.w = f2bf((x.w - mu) * rs * gv.w + 0.125f * bv.w);
  ((ushort4*)(qn + (size_t)row * D2_))[t] = o4;

  // ---- cast k row ----
  const float4 kx = ((const float4*)(k + (size_t)row * D2_))[t];
  ushort4 k4;
  k4.x = f2bf(kx.x); k4.y = f2bf(kx.y); k4.z = f2bf(kx.z); k4.w = f2bf(kx.w);
  ((ushort4*)(kb + (size_t)row * D2_))[t] = k4;

  // ---- w2 (blocks 0..3) ----
  if (row < 4) {
    const int d = row * 256 + t;
    const float4* r  = (const float4*)(fw + (size_t)d * DV_);
    const float4* vv = (const float4*)V;
    float acc = 0.f;
    #pragma unroll
    for (int j = 0; j < 16; ++j) {
      const float4 a = r[j], b = vv[j];
      acc += a.x * b.x + a.y * b.y + a.z * b.z + a.w * b.w;
    }
    w2[d] = acc;
  }
}

// ---------------------------------------------------------------------------
// Kernel 2: attn = masked( qn @ kb^T );  rowsum += per-row sums.
// R7: 512 threads (8 waves), tile 128(m) x 128(n), BK=128 -> 8 K-iters
// (half the barrier drains of R6), LDS 64 KiB -> 2 blocks/CU x 8 waves
// = 16 waves/CU (vs R6's measured 37% from 4-wave blocks).
// LDS layout = DMA order: plane j (8 KiB) holds granule (row, g) at
//   plane (g>>2), offset row*64B + (g&3)*16B.  Forced lane-linear DMA dest
//   IS this layout; frag reads cover a contiguous 1024B span per wave
//   (m134-canonical, conflict-free). No swizzle arithmetic needed.
// MFMA operands swapped (kb first) so reg quad = 4 consecutive attn cols.
// Mask slice prefetched to registers before the K-loop.
// 8 waves: wm = (w>>2)*64, wn = (w&3)*32; frags fm 0..3, fn 0..1.
// ---------------------------------------------------------------------------
__global__ void __launch_bounds__(512, 4) attn_gemm_kernel(
    const unsigned short* __restrict__ qn,   // [B*S, D2] bf16
    const unsigned short* __restrict__ kb,   // [B*S, D2] bf16
    const int* __restrict__ mask,            // [B, S, S] int32
    float* __restrict__ attn,                // [B, S, S] f32
    float* __restrict__ rowsum) {            // [B*S] f32 (pre-zeroed)
  __shared__ __align__(16) unsigned short Asm_[128 * 128];   // 32 KiB
  __shared__ __align__(16) unsigned short Bsm_[128 * 128];   // 32 KiB

  const int t  = threadIdx.x;
  const int bn = blockIdx.x * 128;
  const int bm = blockIdx.y * 128;
  const int bt = blockIdx.z;

  // staging: thread t covers row r = t>>2; op j loads global granule
  // g = j*4 + (t&3)  ->  LDS plane j, offset t*16B (forced dest).
  // 4 consecutive threads cover 64B contiguous global per op -> coalesced.
  const int srow_ = t >> 2;
  const unsigned short* gA = qn + ((size_t)bt * S_LEN + bm + srow_) * D2_ + (t & 3) * 8;
  const unsigned short* gB = kb + ((size_t)bt * S_LEN + bn + srow_) * D2_ + (t & 3) * 8;
  unsigned short* lA = Asm_ + t * 8;
  unsigned short* lB = Bsm_ + t * 8;

  const int lane = t & 63;
  const int w  = t >> 6;
  const int wm = (w >> 2) * 64;   // wave m offset (0/64)
  const int wn = (w & 3) * 32;    // wave n offset (0/32/64/96)
  const int lr = lane & 15;
  const int lg = lane >> 4;

  // mask prefetch: m = bm+wm+fm*16+lr, n0 = bn+wn+fn*16+lg*4
  const int m_base = bm + wm + lr;
  const size_t rb0 = ((size_t)bt * S_LEN) * S_LEN;
  int4 mk[4][2];
  #pragma unroll
  for (int fm = 0; fm < 4; ++fm)
    #pragma unroll
    for (int fn = 0; fn < 2; ++fn)
      mk[fm][fn] = *(const int4*)(mask + rb0 + (size_t)(m_base + fm * 16) * S_LEN
                                  + bn + wn + fn * 16 + lg * 4);

  f32x4 acc[4][2] = {};           // [fm][fn]

  for (int k0 = 0; k0 < D2_; k0 += 128) {
    #pragma unroll
    for (int j = 0; j < 4; ++j) {
      async16(gA + j * 32, lA + j * 4096);   // A plane j
      async16(gB + j * 32, lB + j * 4096);   // B plane j
    }
    gA += 128; gB += 128;
    __syncthreads();   // drains vmcnt(0): staged tile visible

    #pragma unroll
    for (int ks = 0; ks < 4; ++ks) {
      // granule (row, ks*4+lg) -> plane ks, elem ofs row*32 + lg*8
      bf16x8 af[4], bfv[2];
      #pragma unroll
      for (int f = 0; f < 4; ++f)
        af[f]  = *(const bf16x8*)(Asm_ + ks * 4096 + (wm + f * 16 + lr) * 32 + lg * 8);
      #pragma unroll
      for (int f = 0; f < 2; ++f)
        bfv[f] = *(const bf16x8*)(Bsm_ + ks * 4096 + (wn + f * 16 + lr) * 32 + lg * 8);
      #pragma unroll
      for (int fm = 0; fm < 4; ++fm)
        #pragma unroll
        for (int fn = 0; fn < 2; ++fn)
          acc[fm][fn] = __builtin_amdgcn_mfma_f32_16x16x32_bf16(
              bfv[fn], af[fm], acc[fm][fn], 0, 0, 0);   // swapped order
    }
    __syncthreads();   // all reads done before next iter's DMA overwrites
  }

  // epilogue: pure stores (mask already in registers) + rowsum reduce.
  #pragma unroll
  for (int fm = 0; fm < 4; ++fm) {
    const int m = m_base + fm * 16;
    const size_t rowbase = rb0 + (size_t)m * S_LEN;
    float s = 0.f;
    #pragma unroll
    for (int fn = 0; fn < 2; ++fn) {
      const int n0 = bn + wn + fn * 16 + lg * 4;
      float4 v;
      v.x = mk[fm][fn].x ? 0.0f : acc[fm][fn][0];
      v.y = mk[fm][fn].y ? 0.0f : acc[fm][fn][1];
      v.z = mk[fm][fn].z ? 0.0f : acc[fm][fn][2];
      v.w = mk[fm][fn].w ? 0.0f : acc[fm][fn][3];
      *(float4*)(attn + rowbase + n0) = v;
      s += v.x + v.y + v.z + v.w;
    }
    // reduce across the 4 lg groups sharing this row
    s += __shfl_xor(s, 16);
    s += __shfl_xor(s, 32);
    if (lane < 16) atomicAdd(rowsum + (size_t)bt * S_LEN + m, s);
  }
}

// ---------------------------------------------------------------------------
// Kernel 3: out[row,:] = rowsum[row] * w2[:] + fc_b[:] + q[row,:]
// (never touches attn).  Overwrites the out-region that held qn/kb; reads
// nothing from it — safe under stream ordering.
// ---------------------------------------------------------------------------
__global__ void __launch_bounds__(256) out_kernel(
    const float* __restrict__ rowsum, const float* __restrict__ q,
    const float* __restrict__ w2, const float* __restrict__ fcb,
    float* __restrict__ out) {
  const int row = blockIdx.x;
  const int t = threadIdx.x;
  const float rs = rowsum[row];
  const float4 wv = ((const float4*)w2)[t];
  const float4 bv = ((const float4*)fcb)[t];
  const float4 qv = ((const float4*)(q + (size_t)row * D2_))[t];
  float4 o4;
  o4.x = rs * wv.x + bv.x + qv.x;
  o4.y = rs * wv.y + bv.y + qv.y;
  o4.z = rs * wv.z + bv.z + qv.z;
  o4.w = rs * wv.w + bv.w + qv.w;
  ((float4*)(out + (size_t)row * D2_))[t] = o4;
}

// ---------------------------------------------------------------------------
extern "C" void kernel_launch(void* const* d_in, const int* in_sizes, int n_in,
                              void* d_out, int out_size, void* d_ws, size_t ws_size,
                              hipStream_t stream) {
  (void)in_sizes; (void)n_in; (void)out_size; (void)ws_size;
  const float* q    = (const float*)d_in[0];
  const float* k    = (const float*)d_in[1];
  /* d_in[2] == v: provably unused by the reference computation */
  const int*   mask = (const int*)d_in[3];
  const float* V    = (const float*)d_in[4];
  const float* fw   = (const float*)d_in[5];
  const float* fcb  = (const float*)d_in[6];
  const float* lg   = (const float*)d_in[7];
  const float* lb   = (const float*)d_in[8];

  float* out  = (float*)d_out;                          // [B,S,D2]  32 MiB
  float* attn = out + (size_t)NB_ * S_LEN * D2_;        // [B,S,S]   64 MiB

  // qn/kb live INSIDE the out-region (exactly 32 MiB), dead until out_kernel
  // overwrites it last.  d_ws: w2 (4 KiB) + rowsum (32 KiB).
  unsigned short* qn = (unsigned short*)out;                     // 16 MiB
  unsigned short* kb = qn + (size_t)NB_ * S_LEN * D2_;           // 16 MiB
  float* w2     = (float*)d_ws;                                  // 1024 f
  float* rowsum = w2 + D2_;                                      // 8192 f

  prep_kernel<<<NB_ * S_LEN, 256, 0, stream>>>(q, k, lg, lb, V, fw, qn, kb, w2, rowsum);
  attn_gemm_kernel<<<dim3(S_LEN / 128, S_LEN / 128, NB_), 512, 0, stream>>>(qn, kb, mask, attn, rowsum);
  out_kernel<<<NB_ * S_LEN, 256, 0, stream>>>(rowsum, q, w2, fcb, out);
}

// Round 8
// 267.769 us; speedup vs baseline: 1.1970x; 1.0136x over previous
//
#include <hip/hip_runtime.h>
#include <hip/hip_bf16.h>
#include <cstdint>

// Problem constants (B=4, S=2048, D2=1024, DV=64, d_k=64)
#define S_LEN 2048
#define D2_   1024
#define DV_   64
#define NB_   4

typedef __bf16 bf16x8 __attribute__((ext_vector_type(8)));
typedef float  f32x4  __attribute__((ext_vector_type(4)));

// fp32 -> bf16 round-to-nearest-even
__device__ __forceinline__ unsigned short f2bf(float f) {
  union { float f; unsigned int u; } v; v.f = f;
  unsigned int r = v.u + 0x7fffu + ((v.u >> 16) & 1u);
  return (unsigned short)(r >> 16);
}

// async global->LDS, 16B per lane (global_load_lds_dwordx4)
__device__ __forceinline__ void async16(const unsigned short* g, unsigned short* l) {
  __builtin_amdgcn_global_load_lds(
      (__attribute__((address_space(1))) void*)g,
      (__attribute__((address_space(3))) void*)l,
      16, 0, 0);
}

// ---------------------------------------------------------------------------
// Kernel 1 (fused prep): per row r:
//   qn[r,:] = bf16( LN(q[r,:]) * 0.125 )      (1/sqrt(64) folded in)
//   kb[r,:] = bf16( k[r,:] )
//   blocks 0..3:  w2[d] = fc_w[d,:] . V       (rank-1 collapse of @fc_w.T)
//   blocks 0..31: zero rowsum[] (d_ws is poisoned 0xAA before every launch)
// ---------------------------------------------------------------------------
__global__ void __launch_bounds__(256) prep_kernel(
    const float* __restrict__ q, const float* __restrict__ k,
    const float* __restrict__ gam, const float* __restrict__ bet,
    const float* __restrict__ V, const float* __restrict__ fw,
    unsigned short* __restrict__ qn, unsigned short* __restrict__ kb,
    float* __restrict__ w2, float* __restrict__ rowsum) {
  const int row = blockIdx.x;
  const int t = threadIdx.x;

  if (row < 32) rowsum[row * 256 + t] = 0.0f;   // 8192 floats total

  // ---- LN(q) ----
  const float4 x = ((const float4*)(q + (size_t)row * D2_))[t];
  float s  = x.x + x.y + x.z + x.w;
  float ss = x.x * x.x + x.y * x.y + x.z * x.z + x.w * x.w;
  #pragma unroll
  for (int o = 32; o > 0; o >>= 1) { s += __shfl_down(s, o); ss += __shfl_down(ss, o); }
  __shared__ float red[8];
  if ((t & 63) == 0) { red[t >> 6] = s; red[(t >> 6) + 4] = ss; }
  __syncthreads();
  const float tot  = red[0] + red[1] + red[2] + red[3];
  const float tots = red[4] + red[5] + red[6] + red[7];
  const float mu  = tot * (1.0f / D2_);
  const float var = tots * (1.0f / D2_) - mu * mu;
  const float rs  = rsqrtf(var + 1e-6f) * 0.125f;
  const float4 gv = ((const float4*)gam)[t];
  const float4 bv = ((const float4*)bet)[t];
  ushort4 o4;
  o4.x = f2bf((x.x - mu) * rs * gv.x + 0.125f * bv.x);
  o4.y = f2bf((x.y - mu) * rs * gv.y + 0.125f * bv.y);
  o4.z = f2bf((x.z - mu) * rs * gv.z + 0.125f * bv.z);
  o4.w = f2bf((x.w - mu) * rs * gv.w + 0.125f * bv.w);
  ((ushort4*)(qn + (size_t)row * D2_))[t] = o4;

  // ---- cast k row ----
  const float4 kx = ((const float4*)(k + (size_t)row * D2_))[t];
  ushort4 k4;
  k4.x = f2bf(kx.x); k4.y = f2bf(kx.y); k4.z = f2bf(kx.z); k4.w = f2bf(kx.w);
  ((ushort4*)(kb + (size_t)row * D2_))[t] = k4;

  // ---- w2 (blocks 0..3) ----
  if (row < 4) {
    const int d = row * 256 + t;
    const float4* r  = (const float4*)(fw + (size_t)d * DV_);
    const float4* vv = (const float4*)V;
    float acc = 0.f;
    #pragma unroll
    for (int j = 0; j < 16; ++j) {
      const float4 a = r[j], b = vv[j];
      acc += a.x * b.x + a.y * b.y + a.z * b.z + a.w * b.w;
    }
    w2[d] = acc;
  }
}

// ---------------------------------------------------------------------------
// Kernel 2: attn = masked( qn @ kb^T );  rowsum += per-row sums.
// R8: 512 threads (8 waves), tile 128x128, BK=128 (8 K-iters, 8 barrier
// drains) + the R5/R6-PROVEN swizzle restored at 128B row stride:
//   Each matrix = two 16 KiB k-half planes (h = k-granule>>3).
//   Within plane: granule (row, s) at row*128B + (s ^ (row&7))*16B.
//   -> bank quad = pure function of the XOR'd slot: wave spreads over all
//      8 quads at 2-way (free; measured 0 conflicts in R5/R6).
//   R7's 64B-stride layout put 16 lanes on 2 quads -> 6.3M conflicts.
// DMA: op j (j=0..3 per matrix): k-half h=j>>1, row-half rh=j&1; thread t
//   covers row rh*64+(t>>3); forced dest = base + h*16K + rh*8K + t*16B;
//   global granule g = h*8 + ((t&7) ^ (row&7))  (64B-chunk permute, coalesced).
// MFMA operands swapped (kb first) so reg quad = 4 consecutive attn cols.
// Mask slice prefetched to registers before the K-loop.
// 8 waves: wm = (w>>2)*64, wn = (w&3)*32; frags fm 0..3, fn 0..1.
// ---------------------------------------------------------------------------
__global__ void __launch_bounds__(512, 4) attn_gemm_kernel(
    const unsigned short* __restrict__ qn,   // [B*S, D2] bf16
    const unsigned short* __restrict__ kb,   // [B*S, D2] bf16
    const int* __restrict__ mask,            // [B, S, S] int32
    float* __restrict__ attn,                // [B, S, S] f32
    float* __restrict__ rowsum) {            // [B*S] f32 (pre-zeroed)
  __shared__ __align__(16) unsigned short Asm_[2 * 8192];   // 32 KiB
  __shared__ __align__(16) unsigned short Bsm_[2 * 8192];   // 32 KiB

  const int t  = threadIdx.x;
  const int bn = blockIdx.x * 128;
  const int bm = blockIdx.y * 128;
  const int bt = blockIdx.z;

  // staging base: thread t -> row (t>>3), permuted granule (t&7)^(row&7)
  const int srow_ = t >> 3;
  const int pg_   = (t & 7) ^ (srow_ & 7);
  const unsigned short* gA = qn + ((size_t)bt * S_LEN + bm + srow_) * D2_ + pg_ * 8;
  const unsigned short* gB = kb + ((size_t)bt * S_LEN + bn + srow_) * D2_ + pg_ * 8;
  unsigned short* lA = Asm_ + t * 8;
  unsigned short* lB = Bsm_ + t * 8;

  const int lane = t & 63;
  const int w  = t >> 6;
  const int wm = (w >> 2) * 64;   // wave m offset (0/64)
  const int wn = (w & 3) * 32;    // wave n offset (0/32/64/96)
  const int lr = lane & 15;
  const int lg = lane >> 4;

  // mask prefetch: m = bm+wm+fm*16+lr, n0 = bn+wn+fn*16+lg*4
  const int m_base = bm + wm + lr;
  const size_t rb0 = ((size_t)bt * S_LEN) * S_LEN;
  int4 mk[4][2];
  #pragma unroll
  for (int fm = 0; fm < 4; ++fm)
    #pragma unroll
    for (int fn = 0; fn < 2; ++fn)
      mk[fm][fn] = *(const int4*)(mask + rb0 + (size_t)(m_base + fm * 16) * S_LEN
                                  + bn + wn + fn * 16 + lg * 4);

  f32x4 acc[4][2] = {};           // [fm][fn]

  for (int k0 = 0; k0 < D2_; k0 += 128) {
    // op j: k-half h=j>>1 (global +h*64 elems), row-half rh=j&1 (+rh*64 rows)
    #pragma unroll
    for (int j = 0; j < 4; ++j) {
      const int h = j >> 1, rh = j & 1;
      const size_t gofs = (size_t)rh * 64 * D2_ + h * 64;
      const int    lofs = h * 8192 + rh * 4096;
      async16(gA + gofs, lA + lofs);
      async16(gB + gofs, lB + lofs);
    }
    gA += 128; gB += 128;
    __syncthreads();   // drains vmcnt(0): staged tile visible

    #pragma unroll
    for (int ks = 0; ks < 4; ++ks) {
      // chunk ks needs granule ks*4+lg: plane ks>>1, slot ((ks&1)*4+lg)^(row&7)
      const int pl = (ks >> 1) * 8192;
      const int sl = (((ks & 1) << 2) + lg) ^ (lr & 7);   // row&7 == lr&7
      bf16x8 af[4], bfv[2];
      #pragma unroll
      for (int f = 0; f < 4; ++f)
        af[f]  = *(const bf16x8*)(Asm_ + pl + (wm + f * 16 + lr) * 64 + sl * 8);
      #pragma unroll
      for (int f = 0; f < 2; ++f)
        bfv[f] = *(const bf16x8*)(Bsm_ + pl + (wn + f * 16 + lr) * 64 + sl * 8);
      #pragma unroll
      for (int fm = 0; fm < 4; ++fm)
        #pragma unroll
        for (int fn = 0; fn < 2; ++fn)
          acc[fm][fn] = __builtin_amdgcn_mfma_f32_16x16x32_bf16(
              bfv[fn], af[fm], acc[fm][fn], 0, 0, 0);   // swapped order
    }
    __syncthreads();   // all reads done before next iter's DMA overwrites
  }

  // epilogue: pure stores (mask already in registers) + rowsum reduce.
  #pragma unroll
  for (int fm = 0; fm < 4; ++fm) {
    const int m = m_base + fm * 16;
    const size_t rowbase = rb0 + (size_t)m * S_LEN;
    float s = 0.f;
    #pragma unroll
    for (int fn = 0; fn < 2; ++fn) {
      const int n0 = bn + wn + fn * 16 + lg * 4;
      float4 v;
      v.x = mk[fm][fn].x ? 0.0f : acc[fm][fn][0];
      v.y = mk[fm][fn].y ? 0.0f : acc[fm][fn][1];
      v.z = mk[fm][fn].z ? 0.0f : acc[fm][fn][2];
      v.w = mk[fm][fn].w ? 0.0f : acc[fm][fn][3];
      *(float4*)(attn + rowbase + n0) = v;
      s += v.x + v.y + v.z + v.w;
    }
    // reduce across the 4 lg groups sharing this row
    s += __shfl_xor(s, 16);
    s += __shfl_xor(s, 32);
    if (lane < 16) atomicAdd(rowsum + (size_t)bt * S_LEN + m, s);
  }
}

// ---------------------------------------------------------------------------
// Kernel 3: out[row,:] = rowsum[row] * w2[:] + fc_b[:] + q[row,:]
// (never touches attn).  Overwrites the out-region that held qn/kb; reads
// nothing from it — safe under stream ordering.
// ---------------------------------------------------------------------------
__global__ void __launch_bounds__(256) out_kernel(
    const float* __restrict__ rowsum, const float* __restrict__ q,
    const float* __restrict__ w2, const float* __restrict__ fcb,
    float* __restrict__ out) {
  const int row = blockIdx.x;
  const int t = threadIdx.x;
  const float rs = rowsum[row];
  const float4 wv = ((const float4*)w2)[t];
  const float4 bv = ((const float4*)fcb)[t];
  const float4 qv = ((const float4*)(q + (size_t)row * D2_))[t];
  float4 o4;
  o4.x = rs * wv.x + bv.x + qv.x;
  o4.y = rs * wv.y + bv.y + qv.y;
  o4.z = rs * wv.z + bv.z + qv.z;
  o4.w = rs * wv.w + bv.w + qv.w;
  ((float4*)(out + (size_t)row * D2_))[t] = o4;
}

// ---------------------------------------------------------------------------
extern "C" void kernel_launch(void* const* d_in, const int* in_sizes, int n_in,
                              void* d_out, int out_size, void* d_ws, size_t ws_size,
                              hipStream_t stream) {
  (void)in_sizes; (void)n_in; (void)out_size; (void)ws_size;
  const float* q    = (const float*)d_in[0];
  const float* k    = (const float*)d_in[1];
  /* d_in[2] == v: provably unused by the reference computation */
  const int*   mask = (const int*)d_in[3];
  const float* V    = (const float*)d_in[4];
  const float* fw   = (const float*)d_in[5];
  const float* fcb  = (const float*)d_in[6];
  const float* lg   = (const float*)d_in[7];
  const float* lb   = (const float*)d_in[8];

  float* out  = (float*)d_out;                          // [B,S,D2]  32 MiB
  float* attn = out + (size_t)NB_ * S_LEN * D2_;        // [B,S,S]   64 MiB

  // qn/kb live INSIDE the out-region (exactly 32 MiB), dead until out_kernel
  // overwrites it last.  d_ws: w2 (4 KiB) + rowsum (32 KiB).
  unsigned short* qn = (unsigned short*)out;                     // 16 MiB
  unsigned short* kb = qn + (size_t)NB_ * S_LEN * D2_;           // 16 MiB
  float* w2     = (float*)d_ws;                                  // 1024 f
  float* rowsum = w2 + D2_;                                      // 8192 f

  prep_kernel<<<NB_ * S_LEN, 256, 0, stream>>>(q, k, lg, lb, V, fw, qn, kb, w2, rowsum);
  attn_gemm_kernel<<<dim3(S_LEN / 128, S_LEN / 128, NB_), 512, 0, stream>>>(qn, kb, mask, attn, rowsum);
  out_kernel<<<NB_ * S_LEN, 256, 0, stream>>>(rowsum, q, w2, fcb, out);
}